// Round 10
// baseline (543.166 us; speedup 1.0000x reference)
//
#include <hip/hip_runtime.h>
#include <cstddef>

#define NEG_SLOPE 0.2f

typedef __attribute__((ext_vector_type(8))) short bf16x8;
typedef __attribute__((ext_vector_type(4))) float f32x4;

__device__ __forceinline__ float leaky(float v) { return v >= 0.f ? v : NEG_SLOPE * v; }

// pack two f32 into two bf16 (RNE) in one uint: lo = a, hi = b
__device__ __forceinline__ unsigned int bfpack(float a, float b) {
    unsigned int ua = __float_as_uint(a);
    ua += 0x7fffu + ((ua >> 16) & 1u);
    unsigned int ub = __float_as_uint(b);
    ub += 0x7fffu + ((ub >> 16) & 1u);
    return (ua >> 16) | (ub & 0xffff0000u);
}
__device__ __forceinline__ float bflo(unsigned int u) { return __uint_as_float(u << 16); }
__device__ __forceinline__ float bfhi(unsigned int u) { return __uint_as_float(u & 0xffff0000u); }
__device__ __forceinline__ float bfs(unsigned short u) { return __uint_as_float(((unsigned int)u) << 16); }

// ---------- tiny per-relation constants + attention-vector projections ----------
__global__ void k_small(const float* __restrict__ rel_emb, const float* __restrict__ W_relT,
                        const float* __restrict__ W_relprop, const float* __restrict__ b_relprop,
                        const float* __restrict__ W_fuse, const float* __restrict__ W_src,
                        const float* __restrict__ b_src, const float* __restrict__ W_node,
                        const float* __restrict__ b_node,
                        float* __restrict__ relfeat, float* __restrict__ wes, float* __restrict__ wed,
                        float* __restrict__ ces, float* __restrict__ ced) {
    __shared__ float av[512];     // attn vectors [r][h][i][d]
    __shared__ float rp[2][128];  // rel_prop
    int t = threadIdx.x;  // 512 threads
    {
        int r = t >> 8, m = t & 255;
        float acc = 0.f;
        const float* re = rel_emb + r * 64;
        const float* w = W_relT + (size_t)r * 16384 + m;
        #pragma unroll 8
        for (int k = 0; k < 64; ++k) acc += re[k] * w[(size_t)k * 256];
        av[t] = acc;
    }
    if (t < 256) {
        int r = t >> 7, m = t & 127;
        float acc = b_relprop[t];
        const float* re = rel_emb + r * 64;
        const float* w = W_relprop + (size_t)r * 8192 + m;
        #pragma unroll 8
        for (int k = 0; k < 64; ++k) acc += re[k] * w[(size_t)k * 128];
        rp[r][m] = acc;
    }
    __syncthreads();
    if (t < 256) {  // relation fusing feature
        int r = t >> 7, h = (t >> 5) & 3, d = t & 31;
        float acc = 0.f;
        const float* w = W_fuse + ((size_t)(r * 4 + h) * 32) * 32 + d;
        #pragma unroll
        for (int k = 0; k < 32; ++k) acc += rp[r][h * 32 + k] * w[(size_t)k * 32];
        relfeat[t] = acc;
    }
    // project attn vectors through weights so edge scores come straight from x
    for (int idx = t; idx < 2048; idx += 512) {
        int which = idx >> 10, rem = idx & 1023;
        int r = rem >> 9, h = (rem >> 7) & 3, c = rem & 127;
        const float* W = which ? W_node : (W_src + (size_t)r * 16384);
        const float* a = av + r * 256 + h * 64 + which * 32;
        float acc = 0.f;
        #pragma unroll
        for (int d = 0; d < 32; ++d) acc += W[(size_t)c * 128 + h * 32 + d] * a[d];
        (which ? wed : wes)[rem] = acc;
    }
    if (t < 16) {
        int which = t >> 3, r = (t >> 2) & 1, h = t & 3;
        const float* b = which ? b_node : (b_src + r * 128);
        const float* a = av + r * 256 + h * 64 + which * 32;
        float acc = 0.f;
        #pragma unroll
        for (int d = 0; d < 32; ++d) acc += b[h * 32 + d] * a[d];
        (which ? ced : ces)[r * 4 + h] = acc;
    }
}

// ---------- transpose weights to bf16 W^T: wt[mat][n][k] = bf16(W[mat][k][n]) ----------
__global__ void k_twt(const float* __restrict__ Ws, const float* __restrict__ Wn,
                      const float* __restrict__ Wg, unsigned int* __restrict__ wt) {
    int idx = blockIdx.x * 256 + threadIdx.x;   // 4 * 128 * 64 = 32768 uints
    if (idx >= 32768) return;
    int mat = idx >> 13, rem = idx & 8191;
    int nrow = rem >> 6, kp = rem & 63;
    const float* W = mat < 2 ? Ws + (size_t)mat * 16384 : (mat == 2 ? Wn : Wg);
    wt[idx] = bfpack(W[(size_t)(2 * kp) * 128 + nrow], W[(size_t)(2 * kp + 1) * 128 + nrow]);
}

// ---------- CSR build, stage 1: coarse bucket counts (single pass over src+dst) ----------
__global__ __launch_bounds__(256) void k_count(const int* __restrict__ src, const int* __restrict__ dst,
                                               int E, int RE, int* __restrict__ bucketTot) {
    __shared__ int h0[256], h1[256], h2[256];
    int t = threadIdx.x;
    h0[t] = 0; h1[t] = 0; h2[t] = 0;
    __syncthreads();
    int chunk = (RE + gridDim.x - 1) / gridDim.x;
    int lo = blockIdx.x * chunk, hi = min(lo + chunk, RE);
    for (int i = lo + t; i < hi; i += 256) {
        int d = dst[i], s = src[i];
        atomicAdd((i < E ? h0 : h1) + (d >> 9), 1);
        atomicAdd(&h2[s >> 9], 1);
    }
    __syncthreads();
    if (h0[t]) atomicAdd(&bucketTot[t], h0[t]);
    if (h1[t]) atomicAdd(&bucketTot[256 + t], h1[t]);
    if (h2[t]) atomicAdd(&bucketTot[512 + t], h2[t]);
}

// ---------- stage 2: scan bucket totals -> bases + cursors ----------
__global__ __launch_bounds__(256) void k_bases(const int* __restrict__ bucketTot,
                                               int* __restrict__ bucketBase, int* __restrict__ cursor,
                                               int* __restrict__ ip0, int* __restrict__ ip1,
                                               int N, int E) {
    __shared__ int sc[256];
    int t = threadIdx.x;
    for (int j = 0; j < 3; ++j) {
        int v = bucketTot[j * 256 + t];
        sc[t] = v;
        __syncthreads();
        for (int off = 1; off < 256; off <<= 1) {
            int tmp = (t >= off) ? sc[t - off] : 0;
            __syncthreads();
            sc[t] += tmp;
            __syncthreads();
        }
        int excl = sc[t] - v;
        bucketBase[j * 257 + t] = excl;
        if (t == 255) bucketBase[j * 257 + 256] = sc[255];
        cursor[j * 256 + t] = excl;
        __syncthreads();
    }
    if (t == 0) { ip0[N] = E; ip1[N] = E; }
}

// ---------- stage 3: coarse scatter into bucket regions (single pass over src+dst) ----------
__global__ __launch_bounds__(256) void k_cscatter(const int* __restrict__ src, const int* __restrict__ dst,
                                                  int E, int RE, int* __restrict__ cursor,
                                                  uint2* __restrict__ pairs0, uint2* __restrict__ pairs1,
                                                  int* __restrict__ svals) {
    __shared__ int h0[256], h1[256], h2[256];
    __shared__ int c0[256], c1[256], c2[256];
    int t = threadIdx.x;
    h0[t] = 0; h1[t] = 0; h2[t] = 0;
    __syncthreads();
    int chunk = (RE + gridDim.x - 1) / gridDim.x;
    int lo = blockIdx.x * chunk, hi = min(lo + chunk, RE);
    for (int i = lo + t; i < hi; i += 256) {
        int d = dst[i], s = src[i];
        atomicAdd((i < E ? h0 : h1) + (d >> 9), 1);
        atomicAdd(&h2[s >> 9], 1);
    }
    __syncthreads();
    if (h0[t]) c0[t] = atomicAdd(&cursor[t], h0[t]);
    if (h1[t]) c1[t] = atomicAdd(&cursor[256 + t], h1[t]);
    if (h2[t]) c2[t] = atomicAdd(&cursor[512 + t], h2[t]);
    __syncthreads();
    for (int i = lo + t; i < hi; i += 256) {
        int d = dst[i], s = src[i];
        if (i < E) {
            int pos = atomicAdd(&c0[d >> 9], 1);
            pairs0[pos] = make_uint2((unsigned)s, (unsigned)d);
        } else {
            int pos = atomicAdd(&c1[d >> 9], 1);
            pairs1[pos] = make_uint2((unsigned)s, (unsigned)d);
        }
        int pos2 = atomicAdd(&c2[s >> 9], 1);
        svals[pos2] = s;
    }
}

// ---------- stage 4 (3 jobs): per-bucket fine sort (r=0,1) + src out-degree -> rsdo (r=2) ----------
__global__ __launch_bounds__(512) void k_fine(const uint2* __restrict__ pairs0, const uint2* __restrict__ pairs1,
                                              const int* __restrict__ svals,
                                              const int* __restrict__ bucketBase,
                                              int* __restrict__ ip0, int* __restrict__ ip1,
                                              int* __restrict__ srcs0, int* __restrict__ srcs1,
                                              float* __restrict__ rsdo, int N) {
    int r = blockIdx.y;
    int b = blockIdx.x;
    __shared__ int hist[512];
    int t = threadIdx.x;
    hist[t] = 0;
    __syncthreads();
    if (r == 2) {   // src out-degree histogram
        int ebase = bucketBase[2 * 257 + b], eend = bucketBase[2 * 257 + b + 1];
        for (int k = ebase + t; k < eend; k += 512)
            atomicAdd(&hist[svals[k] & 511], 1);
        __syncthreads();
        int node = (b << 9) + t;
        if (node < N) rsdo[node] = rsqrtf(fmaxf((float)hist[t], 1.f));
        return;
    }
    const uint2* pairs = r ? pairs1 : pairs0;
    int* ip = r ? ip1 : ip0;
    int* srcs = r ? srcs1 : srcs0;
    int ebase = bucketBase[r * 257 + b], eend = bucketBase[r * 257 + b + 1];
    for (int k = ebase + t; k < eend; k += 512)
        atomicAdd(&hist[pairs[k].y & 511], 1);
    __syncthreads();
    int v = hist[t];
    for (int off = 1; off < 512; off <<= 1) {
        int tmp = (t >= off) ? hist[t - off] : 0;
        __syncthreads();
        hist[t] += tmp;
        __syncthreads();
    }
    int excl = hist[t] - v;
    int node = (b << 9) + t;
    if (node < N) ip[node] = ebase + excl;
    __syncthreads();
    hist[t] = ebase + excl;  // reuse as scatter cursor
    __syncthreads();
    for (int k = ebase + t; k < eend; k += 512) {
        uint2 p = pairs[k];
        int pos = atomicAdd(&hist[p.y & 511], 1);
        srcs[pos] = (int)p.x;
    }
}

// ---------- fused prep + dual-relation MFMA GEMM: 128-row tile ----------
// gx[node] = fs0(64 uints) | fs1(64) | xb(64)  (768B interleaved rows)
__global__ __launch_bounds__(256) void k_prepmm(const float* __restrict__ x,
                                                const float* __restrict__ wes, const float* __restrict__ wed,
                                                const float* __restrict__ ces, const float* __restrict__ ced,
                                                const unsigned short* __restrict__ wts,
                                                const float* __restrict__ b_src,
                                                float* __restrict__ es0, float* __restrict__ es1,
                                                float* __restrict__ ed0, float* __restrict__ ed1,
                                                unsigned int* __restrict__ gx, int n) {
    __shared__ unsigned int xsb[128 * 64];   // bf16-pair rows, 32 KB
    int tid = threadIdx.x;
    int nb0 = blockIdx.x * 128;
    // stage 1: load x (f32) -> bf16 pairs -> LDS + gx xb section
    for (int i = tid; i < 128 * 32; i += 256) {
        int row = i >> 5, c4 = i & 31;
        int gr = nb0 + row;
        uint2 w = make_uint2(0u, 0u);
        if (gr < n) {
            float4 v = *(const float4*)(x + (size_t)gr * 128 + c4 * 4);
            w.x = bfpack(v.x, v.y);
            w.y = bfpack(v.z, v.w);
            *(uint2*)(gx + (size_t)gr * 192 + 128 + c4 * 2) = w;
        }
        *(uint2*)(xsb + row * 64 + c4 * 2) = w;
    }
    __syncthreads();
    // stage 2: per-node attention scores (from bf16 LDS copy)
    #pragma unroll
    for (int q = 0; q < 8; ++q) {
        int item = tid + q * 256;            // 128 nodes x 16 outputs
        int node = item >> 4, j = item & 15; // j = which*8 + r*4 + h
        int gn = nb0 + node;
        if (gn < n) {
            int which = j >> 3, r = (j >> 2) & 1, h = j & 3;
            const float* w = (which ? wed : wes) + r * 512 + h * 128;
            float acc = (which ? ced : ces)[r * 4 + h];
            const unsigned int* xr = xsb + node * 64;
            #pragma unroll 16
            for (int c2 = 0; c2 < 64; ++c2) {
                unsigned int u = xr[c2];
                acc += bflo(u) * w[2 * c2] + bfhi(u) * w[2 * c2 + 1];
            }
            float* outp = which ? (r ? ed1 : ed0) : (r ? es1 : es0);
            outp[(size_t)gn * 4 + h] = acc;
        }
    }
    // stage 3: dual-relation MFMA GEMM from LDS A-fragments
    int wid = tid >> 6, lane = tid & 63;
    int l15 = lane & 15, g = lane >> 4;
    int m0l = wid * 32;                      // local row base
    f32x4 acc[2][2][8];
    #pragma unroll
    for (int rel = 0; rel < 2; ++rel)
        #pragma unroll
        for (int mt = 0; mt < 2; ++mt)
            #pragma unroll
            for (int nt = 0; nt < 8; ++nt)
                #pragma unroll
                for (int r = 0; r < 4; ++r) acc[rel][mt][nt][r] = 0.f;
    const unsigned short* wt0 = wts;
    const unsigned short* wt1 = wts + 16384;
    #pragma unroll
    for (int t = 0; t < 4; ++t) {
        bf16x8 a0 = *(const bf16x8*)(xsb + (m0l + l15) * 64 + t * 16 + g * 4);
        bf16x8 a1 = *(const bf16x8*)(xsb + (m0l + 16 + l15) * 64 + t * 16 + g * 4);
        #pragma unroll
        for (int nt = 0; nt < 8; ++nt) {
            bf16x8 b0 = *(const bf16x8*)(wt0 + (size_t)(nt * 16 + l15) * 128 + t * 32 + g * 8);
            bf16x8 b1 = *(const bf16x8*)(wt1 + (size_t)(nt * 16 + l15) * 128 + t * 32 + g * 8);
            acc[0][0][nt] = __builtin_amdgcn_mfma_f32_16x16x32_bf16(a0, b0, acc[0][0][nt], 0, 0, 0);
            acc[0][1][nt] = __builtin_amdgcn_mfma_f32_16x16x32_bf16(a1, b0, acc[0][1][nt], 0, 0, 0);
            acc[1][0][nt] = __builtin_amdgcn_mfma_f32_16x16x32_bf16(a0, b1, acc[1][0][nt], 0, 0, 0);
            acc[1][1][nt] = __builtin_amdgcn_mfma_f32_16x16x32_bf16(a1, b1, acc[1][1][nt], 0, 0, 0);
        }
    }
    #pragma unroll
    for (int rel = 0; rel < 2; ++rel)
        #pragma unroll
        for (int mt = 0; mt < 2; ++mt)
            #pragma unroll
            for (int nt = 0; nt < 8; ++nt) {
                int col = nt * 16 + l15;
                float bv = b_src[rel * 128 + col];
                #pragma unroll
                for (int r = 0; r < 4; ++r) {
                    int row = nb0 + m0l + mt * 16 + g * 4 + r;
                    float v = acc[rel][mt][nt][r] + bv;
                    float vp = __shfl_xor(v, 1);
                    if (!(l15 & 1) && row < n)
                        gx[(size_t)row * 192 + rel * 64 + (col >> 1)] = bfpack(v, vp);
                }
            }
}

// ---------- merged CSR gather-aggregate: one wave per node; fused relation softmax; bf16 outputs ----------
__global__ __launch_bounds__(256) void k_agg(const int* __restrict__ ip0, const int* __restrict__ srcs0,
                                             const int* __restrict__ ip1, const int* __restrict__ srcs1,
                                             const unsigned int* __restrict__ gx,
                                             const float* __restrict__ es0, const float* __restrict__ es1,
                                             const float* __restrict__ ed0, const float* __restrict__ ed1,
                                             const float* __restrict__ rsdo,
                                             const float* __restrict__ relfeat,
                                             unsigned int* __restrict__ fubp, unsigned int* __restrict__ hgbp, int n) {
    int node = blockIdx.x * 4 + (threadIdx.x >> 6);   // one 64-lane wave per node
    if (node >= n) return;
    int j2 = threadIdx.x & 63;                        // channel pair (2*j2, 2*j2+1)
    int h = j2 >> 4;
    float ed0v = ed0[(size_t)node * 4 + h];
    float ed1v = ed1[(size_t)node * 4 + h];
    float aU0x = 0.f, aU0y = 0.f, aU1x = 0.f, aU1y = 0.f, aHx = 0.f, aHy = 0.f;
    float s0 = 0.f, s1 = 0.f;
    int b0 = ip0[node], e0 = ip0[node + 1];
    #pragma unroll 4
    for (int k = b0; k < e0; ++k) {
        int s = srcs0[k];
        float ex = __expf(leaky(es0[(size_t)s * 4 + h] + ed0v));
        size_t base = (size_t)s * 192;
        unsigned int fv = gx[base + j2];
        unsigned int xv = gx[base + 128 + j2];
        float rs = rsdo[s];
        aU0x += ex * bflo(fv); aU0y += ex * bfhi(fv);
        aHx += rs * bflo(xv); aHy += rs * bfhi(xv);
        s0 += ex;
    }
    int b1 = ip1[node], e1 = ip1[node + 1];
    #pragma unroll 4
    for (int k = b1; k < e1; ++k) {
        int s = srcs1[k];
        float ex = __expf(leaky(es1[(size_t)s * 4 + h] + ed1v));
        size_t base = (size_t)s * 192;
        unsigned int fv = gx[base + 64 + j2];
        unsigned int xv = gx[base + 128 + j2];
        float rs = rsdo[s];
        aU1x += ex * bflo(fv); aU1y += ex * bfhi(fv);
        aHx += rs * bflo(xv); aHy += rs * bfhi(xv);
        s1 += ex;
    }
    float i0 = 1.f / (s0 + 1e-9f), i1 = 1.f / (s1 + 1e-9f);
    float f0x = fmaxf(aU0x * i0, 0.f), f0y = fmaxf(aU0y * i0, 0.f);
    float f1x = fmaxf(aU1x * i1, 0.f), f1y = fmaxf(aU1y * i1, 0.f);
    float sc0 = f0x * relfeat[2 * j2] + f0y * relfeat[2 * j2 + 1];
    float sc1 = f1x * relfeat[128 + 2 * j2] + f1y * relfeat[128 + 2 * j2 + 1];
    #pragma unroll
    for (int m = 1; m < 16; m <<= 1) {
        sc0 += __shfl_xor(sc0, m, 64);
        sc1 += __shfl_xor(sc1, m, 64);
    }
    sc0 = leaky(sc0); sc1 = leaky(sc1);
    float mx = fmaxf(sc0, sc1);
    float p0 = __expf(sc0 - mx), p1 = __expf(sc1 - mx);
    float inv = 1.f / (p0 + p1);
    p0 *= inv; p1 *= inv;
    float rv = rsqrtf(fmaxf((float)((e0 - b0) + (e1 - b1)), 1.f));
    fubp[(size_t)node * 64 + j2] = bfpack(p0 * f0x + p1 * f1x, p0 * f0y + p1 * f1y);
    hgbp[(size_t)node * 64 + j2] = bfpack(aHx * rv, aHy * rv);
}

// ---------- final: two MFMA GEMMs (hgb @ Wg, xb @ Wn) + fusion epilogue ----------
__global__ __launch_bounds__(256) void k_fin(const unsigned int* __restrict__ hgbp,
                                             const unsigned int* __restrict__ gx,
                                             const unsigned short* __restrict__ wtg,
                                             const unsigned short* __restrict__ wtn,
                                             const float* __restrict__ bg, const float* __restrict__ bn,
                                             const unsigned int* __restrict__ fubp,
                                             const float* __restrict__ residual_w, const float* __restrict__ scale_w,
                                             float* __restrict__ out, int n) {
    int wid = threadIdx.x >> 6, lane = threadIdx.x & 63;
    int l15 = lane & 15, g = lane >> 4;
    int m0 = blockIdx.x * 128 + wid * 32;
    const unsigned short* Hu = (const unsigned short*)hgbp;
    const unsigned short* Xu = (const unsigned short*)gx;   // xb at row*384 + 256
    const unsigned short* Fu = (const unsigned short*)fubp;
    f32x4 accn[2][8], accg[2][8];
    #pragma unroll
    for (int mt = 0; mt < 2; ++mt)
        #pragma unroll
        for (int nt = 0; nt < 8; ++nt)
            #pragma unroll
            for (int r = 0; r < 4; ++r) { accn[mt][nt][r] = 0.f; accg[mt][nt][r] = 0.f; }
    #pragma unroll
    for (int t = 0; t < 4; ++t) {
        bf16x8 a0 = *(const bf16x8*)(Xu + (size_t)(m0 + l15) * 384 + 256 + t * 32 + g * 8);
        bf16x8 a1 = *(const bf16x8*)(Xu + (size_t)(m0 + 16 + l15) * 384 + 256 + t * 32 + g * 8);
        #pragma unroll
        for (int nt = 0; nt < 8; ++nt) {
            bf16x8 b = *(const bf16x8*)(wtn + (size_t)(nt * 16 + l15) * 128 + t * 32 + g * 8);
            accn[0][nt] = __builtin_amdgcn_mfma_f32_16x16x32_bf16(a0, b, accn[0][nt], 0, 0, 0);
            accn[1][nt] = __builtin_amdgcn_mfma_f32_16x16x32_bf16(a1, b, accn[1][nt], 0, 0, 0);
        }
    }
    #pragma unroll
    for (int t = 0; t < 4; ++t) {
        bf16x8 a0 = *(const bf16x8*)(Hu + (size_t)(m0 + l15) * 128 + t * 32 + g * 8);
        bf16x8 a1 = *(const bf16x8*)(Hu + (size_t)(m0 + 16 + l15) * 128 + t * 32 + g * 8);
        #pragma unroll
        for (int nt = 0; nt < 8; ++nt) {
            bf16x8 b = *(const bf16x8*)(wtg + (size_t)(nt * 16 + l15) * 128 + t * 32 + g * 8);
            accg[0][nt] = __builtin_amdgcn_mfma_f32_16x16x32_bf16(a0, b, accg[0][nt], 0, 0, 0);
            accg[1][nt] = __builtin_amdgcn_mfma_f32_16x16x32_bf16(a1, b, accg[1][nt], 0, 0, 0);
        }
    }
    float beta = 1.f / (1.f + __expf(-residual_w[0]));
    float av = 1.f / (1.f + __expf(-scale_w[0]));
    #pragma unroll
    for (int mt = 0; mt < 2; ++mt)
        #pragma unroll
        for (int nt = 0; nt < 8; ++nt) {
            int col = nt * 16 + l15;
            float bnv = bn[col], bgv = bg[col];
            #pragma unroll
            for (int r = 0; r < 4; ++r) {
                int row = m0 + mt * 16 + g * 4 + r;
                if (row < n) {
                    float fu = bfs(Fu[(size_t)row * 128 + col]);
                    float fd = accn[mt][nt][r] + bnv;
                    float f = beta * fu + (1.f - beta) * fd;
                    float nl = fmaxf(accg[mt][nt][r] + bgv, 0.f);
                    out[(size_t)row * 128 + col] = av * f + (1.f - av) * nl;
                }
            }
        }
}

extern "C" void kernel_launch(void* const* d_in, const int* in_sizes, int n_in,
                              void* d_out, int out_size, void* d_ws, size_t ws_size,
                              hipStream_t stream) {
    const float* x         = (const float*)d_in[0];
    const int*   src       = (const int*)d_in[1];
    const int*   dst       = (const int*)d_in[2];
    const float* rel_emb   = (const float*)d_in[3];
    const float* W_node    = (const float*)d_in[4];
    const float* b_node    = (const float*)d_in[5];
    const float* W_src     = (const float*)d_in[6];
    const float* b_src     = (const float*)d_in[7];
    const float* W_relT    = (const float*)d_in[8];
    const float* W_relprop = (const float*)d_in[9];
    const float* b_relprop = (const float*)d_in[10];
    const float* W_fuse    = (const float*)d_in[11];
    const float* resid_w   = (const float*)d_in[12];
    const float* scale_w   = (const float*)d_in[13];
    const float* W_g       = (const float*)d_in[14];
    const float* b_g       = (const float*)d_in[15];
    float* out = (float*)d_out;

    const int N = in_sizes[0] / 128;
    const int RE = in_sizes[1];
    const int E = RE / 2;
    const int Npad = (N + 127) & ~127;
    const int NBUCK = (N + 511) >> 9;

    // workspace (~144 MB at N=1e5, E=1e6)
    float* ws = (float*)d_ws;
    size_t o = 0;
    unsigned int* fubp = (unsigned int*)(ws + o); o += (size_t)Npad * 64;   // fused bf16; aliased by sort scratch early
    unsigned int* gx   = (unsigned int*)(ws + o); o += (size_t)Npad * 192;  // fs0|fs1|xb interleaved (768B rows)
    unsigned int* hgbp = (unsigned int*)(ws + o); o += (size_t)Npad * 64;   // bf16 hg*rsdi
    float* es0  = ws + o; o += (size_t)N * 4;
    float* es1  = ws + o; o += (size_t)N * 4;
    float* ed0  = ws + o; o += (size_t)N * 4;
    float* ed1  = ws + o; o += (size_t)N * 4;
    float* rsdo = ws + o; o += N;
    unsigned int* wtu = (unsigned int*)(ws + o); o += 32768;  // bf16 W^T x4 mats
    float* relfeat = ws + o; o += 256;
    float* wes  = ws + o; o += 1024;
    float* wed  = ws + o; o += 1024;
    float* ces  = ws + o; o += 16;
    float* ced  = ws + o; o += 16;
    int* ip0  = (int*)(ws + o); o += N + 1;
    int* ip1  = (int*)(ws + o); o += N + 1;
    int* srcs0 = (int*)(ws + o); o += E;
    int* srcs1 = (int*)(ws + o); o += E;
    int* bucketTot  = (int*)(ws + o); o += 768;
    int* bucketBase = (int*)(ws + o); o += 771;
    int* cursor     = (int*)(ws + o); o += 768;
    // transient sort scratch aliased into fubp region (24 MB <= Npad*256B)
    uint2* pairs0 = (uint2*)fubp;
    uint2* pairs1 = pairs0 + (size_t)E;
    int*   svals  = (int*)(pairs1 + (size_t)E);

    const unsigned short* wts = (const unsigned short*)wtu;  // mat m at wts + m*16384

    hipMemsetAsync(bucketTot, 0, 768 * sizeof(int), stream);

    k_small<<<1, 512, 0, stream>>>(rel_emb, W_relT, W_relprop, b_relprop, W_fuse,
                                   W_src, b_src, W_node, b_node,
                                   relfeat, wes, wed, ces, ced);
    k_twt<<<128, 256, 0, stream>>>(W_src, W_node, W_g, wtu);
    k_count<<<256, 256, 0, stream>>>(src, dst, E, RE, bucketTot);
    k_bases<<<1, 256, 0, stream>>>(bucketTot, bucketBase, cursor, ip0, ip1, N, E);
    k_cscatter<<<256, 256, 0, stream>>>(src, dst, E, RE, cursor, pairs0, pairs1, svals);
    k_fine<<<dim3(NBUCK, 3), 512, 0, stream>>>(pairs0, pairs1, svals, bucketBase,
                                               ip0, ip1, srcs0, srcs1, rsdo, N);

    k_prepmm<<<Npad / 128, 256, 0, stream>>>(x, wes, wed, ces, ced, wts, b_src,
                                             es0, es1, ed0, ed1, gx, N);

    k_agg<<<(N + 3) / 4, 256, 0, stream>>>(ip0, srcs0, ip1, srcs1, gx,
                                           es0, es1, ed0, ed1, rsdo, relfeat, fubp, hgbp, N);

    k_fin<<<Npad / 128, 256, 0, stream>>>(hgbp, gx, wts + 3 * 16384, wts + 2 * 16384,
                                          b_g, b_node, fubp, resid_w, scale_w, out, N);
}

// Round 11
// 512.475 us; speedup vs baseline: 1.0599x; 1.0599x over previous
//
#include <hip/hip_runtime.h>
#include <cstddef>

#define NEG_SLOPE 0.2f

typedef __attribute__((ext_vector_type(8))) short bf16x8;
typedef __attribute__((ext_vector_type(4))) float f32x4;

__device__ __forceinline__ float leaky(float v) { return v >= 0.f ? v : NEG_SLOPE * v; }

// pack two f32 into two bf16 (RNE) in one uint: lo = a, hi = b
__device__ __forceinline__ unsigned int bfpack(float a, float b) {
    unsigned int ua = __float_as_uint(a);
    ua += 0x7fffu + ((ua >> 16) & 1u);
    unsigned int ub = __float_as_uint(b);
    ub += 0x7fffu + ((ub >> 16) & 1u);
    return (ua >> 16) | (ub & 0xffff0000u);
}
__device__ __forceinline__ float bflo(unsigned int u) { return __uint_as_float(u << 16); }
__device__ __forceinline__ float bfhi(unsigned int u) { return __uint_as_float(u & 0xffff0000u); }
__device__ __forceinline__ float bfs(unsigned short u) { return __uint_as_float(((unsigned int)u) << 16); }

// ---------- tiny per-relation constants + attention-vector projections ----------
__global__ void k_small(const float* __restrict__ rel_emb, const float* __restrict__ W_relT,
                        const float* __restrict__ W_relprop, const float* __restrict__ b_relprop,
                        const float* __restrict__ W_fuse, const float* __restrict__ W_src,
                        const float* __restrict__ b_src, const float* __restrict__ W_node,
                        const float* __restrict__ b_node,
                        float* __restrict__ relfeat, float* __restrict__ wes, float* __restrict__ wed,
                        float* __restrict__ ces, float* __restrict__ ced) {
    __shared__ float av[512];     // attn vectors [r][h][i][d]
    __shared__ float rp[2][128];  // rel_prop
    int t = threadIdx.x;  // 512 threads
    {
        int r = t >> 8, m = t & 255;
        float acc = 0.f;
        const float* re = rel_emb + r * 64;
        const float* w = W_relT + (size_t)r * 16384 + m;
        #pragma unroll 8
        for (int k = 0; k < 64; ++k) acc += re[k] * w[(size_t)k * 256];
        av[t] = acc;
    }
    if (t < 256) {
        int r = t >> 7, m = t & 127;
        float acc = b_relprop[t];
        const float* re = rel_emb + r * 64;
        const float* w = W_relprop + (size_t)r * 8192 + m;
        #pragma unroll 8
        for (int k = 0; k < 64; ++k) acc += re[k] * w[(size_t)k * 128];
        rp[r][m] = acc;
    }
    __syncthreads();
    if (t < 256) {  // relation fusing feature
        int r = t >> 7, h = (t >> 5) & 3, d = t & 31;
        float acc = 0.f;
        const float* w = W_fuse + ((size_t)(r * 4 + h) * 32) * 32 + d;
        #pragma unroll
        for (int k = 0; k < 32; ++k) acc += rp[r][h * 32 + k] * w[(size_t)k * 32];
        relfeat[t] = acc;
    }
    // project attn vectors through weights so edge scores come straight from x
    for (int idx = t; idx < 2048; idx += 512) {
        int which = idx >> 10, rem = idx & 1023;
        int r = rem >> 9, h = (rem >> 7) & 3, c = rem & 127;
        const float* W = which ? W_node : (W_src + (size_t)r * 16384);
        const float* a = av + r * 256 + h * 64 + which * 32;
        float acc = 0.f;
        #pragma unroll
        for (int d = 0; d < 32; ++d) acc += W[(size_t)c * 128 + h * 32 + d] * a[d];
        (which ? wed : wes)[rem] = acc;
    }
    if (t < 16) {
        int which = t >> 3, r = (t >> 2) & 1, h = t & 3;
        const float* b = which ? b_node : (b_src + r * 128);
        const float* a = av + r * 256 + h * 64 + which * 32;
        float acc = 0.f;
        #pragma unroll
        for (int d = 0; d < 32; ++d) acc += b[h * 32 + d] * a[d];
        (which ? ced : ces)[r * 4 + h] = acc;
    }
}

// ---------- transpose weights to bf16 W^T: wt[mat][n][k] = bf16(W[mat][k][n]) ----------
__global__ void k_twt(const float* __restrict__ Ws, const float* __restrict__ Wn,
                      const float* __restrict__ Wg, unsigned int* __restrict__ wt) {
    int idx = blockIdx.x * 256 + threadIdx.x;   // 4 * 128 * 64 = 32768 uints
    if (idx >= 32768) return;
    int mat = idx >> 13, rem = idx & 8191;
    int nrow = rem >> 6, kp = rem & 63;
    const float* W = mat < 2 ? Ws + (size_t)mat * 16384 : (mat == 2 ? Wn : Wg);
    wt[idx] = bfpack(W[(size_t)(2 * kp) * 128 + nrow], W[(size_t)(2 * kp + 1) * 128 + nrow]);
}

// ---------- CSR build, stage 1: coarse bucket counts (single pass over src+dst) ----------
__global__ __launch_bounds__(256) void k_count(const int* __restrict__ src, const int* __restrict__ dst,
                                               int E, int RE, int* __restrict__ bucketTot) {
    __shared__ int h0[256], h1[256], h2[256];
    int t = threadIdx.x;
    h0[t] = 0; h1[t] = 0; h2[t] = 0;
    __syncthreads();
    int chunk = (RE + gridDim.x - 1) / gridDim.x;
    int lo = blockIdx.x * chunk, hi = min(lo + chunk, RE);
    for (int i = lo + t; i < hi; i += 256) {
        int d = dst[i], s = src[i];
        atomicAdd((i < E ? h0 : h1) + (d >> 9), 1);
        atomicAdd(&h2[s >> 9], 1);
    }
    __syncthreads();
    if (h0[t]) atomicAdd(&bucketTot[t], h0[t]);
    if (h1[t]) atomicAdd(&bucketTot[256 + t], h1[t]);
    if (h2[t]) atomicAdd(&bucketTot[512 + t], h2[t]);
}

// ---------- stage 2: scan bucket totals -> bases + cursors ----------
__global__ __launch_bounds__(256) void k_bases(const int* __restrict__ bucketTot,
                                               int* __restrict__ bucketBase, int* __restrict__ cursor,
                                               int* __restrict__ ip0, int* __restrict__ ip1,
                                               int N, int E) {
    __shared__ int sc[256];
    int t = threadIdx.x;
    for (int j = 0; j < 3; ++j) {
        int v = bucketTot[j * 256 + t];
        sc[t] = v;
        __syncthreads();
        for (int off = 1; off < 256; off <<= 1) {
            int tmp = (t >= off) ? sc[t - off] : 0;
            __syncthreads();
            sc[t] += tmp;
            __syncthreads();
        }
        int excl = sc[t] - v;
        bucketBase[j * 257 + t] = excl;
        if (t == 255) bucketBase[j * 257 + 256] = sc[255];
        cursor[j * 256 + t] = excl;
        __syncthreads();
    }
    if (t == 0) { ip0[N] = E; ip1[N] = E; }
}

// ---------- stage 3: coarse scatter into bucket regions (single pass over src+dst) ----------
__global__ __launch_bounds__(256) void k_cscatter(const int* __restrict__ src, const int* __restrict__ dst,
                                                  int E, int RE, int* __restrict__ cursor,
                                                  uint2* __restrict__ pairs0, uint2* __restrict__ pairs1,
                                                  int* __restrict__ svals) {
    __shared__ int h0[256], h1[256], h2[256];
    __shared__ int c0[256], c1[256], c2[256];
    int t = threadIdx.x;
    h0[t] = 0; h1[t] = 0; h2[t] = 0;
    __syncthreads();
    int chunk = (RE + gridDim.x - 1) / gridDim.x;
    int lo = blockIdx.x * chunk, hi = min(lo + chunk, RE);
    for (int i = lo + t; i < hi; i += 256) {
        int d = dst[i], s = src[i];
        atomicAdd((i < E ? h0 : h1) + (d >> 9), 1);
        atomicAdd(&h2[s >> 9], 1);
    }
    __syncthreads();
    if (h0[t]) c0[t] = atomicAdd(&cursor[t], h0[t]);
    if (h1[t]) c1[t] = atomicAdd(&cursor[256 + t], h1[t]);
    if (h2[t]) c2[t] = atomicAdd(&cursor[512 + t], h2[t]);
    __syncthreads();
    for (int i = lo + t; i < hi; i += 256) {
        int d = dst[i], s = src[i];
        if (i < E) {
            int pos = atomicAdd(&c0[d >> 9], 1);
            pairs0[pos] = make_uint2((unsigned)s, (unsigned)d);
        } else {
            int pos = atomicAdd(&c1[d >> 9], 1);
            pairs1[pos] = make_uint2((unsigned)s, (unsigned)d);
        }
        int pos2 = atomicAdd(&c2[s >> 9], 1);
        svals[pos2] = s;
    }
}

// ---------- stage 4 (3 jobs): per-bucket fine sort (r=0,1) + src out-degree -> rsdo (r=2) ----------
__global__ __launch_bounds__(512) void k_fine(const uint2* __restrict__ pairs0, const uint2* __restrict__ pairs1,
                                              const int* __restrict__ svals,
                                              const int* __restrict__ bucketBase,
                                              int* __restrict__ ip0, int* __restrict__ ip1,
                                              int* __restrict__ srcs0, int* __restrict__ srcs1,
                                              float* __restrict__ rsdo, int N) {
    int r = blockIdx.y;
    int b = blockIdx.x;
    __shared__ int hist[512];
    int t = threadIdx.x;
    hist[t] = 0;
    __syncthreads();
    if (r == 2) {   // src out-degree histogram
        int ebase = bucketBase[2 * 257 + b], eend = bucketBase[2 * 257 + b + 1];
        for (int k = ebase + t; k < eend; k += 512)
            atomicAdd(&hist[svals[k] & 511], 1);
        __syncthreads();
        int node = (b << 9) + t;
        if (node < N) rsdo[node] = rsqrtf(fmaxf((float)hist[t], 1.f));
        return;
    }
    const uint2* pairs = r ? pairs1 : pairs0;
    int* ip = r ? ip1 : ip0;
    int* srcs = r ? srcs1 : srcs0;
    int ebase = bucketBase[r * 257 + b], eend = bucketBase[r * 257 + b + 1];
    for (int k = ebase + t; k < eend; k += 512)
        atomicAdd(&hist[pairs[k].y & 511], 1);
    __syncthreads();
    int v = hist[t];
    for (int off = 1; off < 512; off <<= 1) {
        int tmp = (t >= off) ? hist[t - off] : 0;
        __syncthreads();
        hist[t] += tmp;
        __syncthreads();
    }
    int excl = hist[t] - v;
    int node = (b << 9) + t;
    if (node < N) ip[node] = ebase + excl;
    __syncthreads();
    hist[t] = ebase + excl;  // reuse as scatter cursor
    __syncthreads();
    for (int k = ebase + t; k < eend; k += 512) {
        uint2 p = pairs[k];
        int pos = atomicAdd(&hist[p.y & 511], 1);
        srcs[pos] = (int)p.x;
    }
}

// ---------- per-node attention scores + xb = bf16(x) into gx xb-section ----------
__global__ __launch_bounds__(256) void k_prep(const float* __restrict__ x,
                                              const float* __restrict__ wes, const float* __restrict__ wed,
                                              const float* __restrict__ ces, const float* __restrict__ ced,
                                              float* __restrict__ es0, float* __restrict__ es1,
                                              float* __restrict__ ed0, float* __restrict__ ed1,
                                              unsigned int* __restrict__ gx, int n) {
    __shared__ float xs[64 * 132];
    int tid = threadIdx.x;
    int nb0 = blockIdx.x * 64;
    for (int i = tid; i < 64 * 32; i += 256) {
        int row = i >> 5, c4 = i & 31;
        float4 v = make_float4(0.f, 0.f, 0.f, 0.f);
        if (nb0 + row < n) v = *(const float4*)(x + (size_t)(nb0 + row) * 128 + c4 * 4);
        *(float4*)(xs + row * 132 + c4 * 4) = v;
    }
    __syncthreads();
    for (int i = tid; i < 64 * 64; i += 256) {
        int row = i >> 6, c2 = i & 63;
        int gr = nb0 + row;
        if (gr < n)
            gx[(size_t)gr * 192 + 128 + c2] = bfpack(xs[row * 132 + 2 * c2], xs[row * 132 + 2 * c2 + 1]);
    }
    int node = tid >> 2;
    int gn = nb0 + node;
    if (gn >= n) return;
    #pragma unroll
    for (int q = 0; q < 4; ++q) {
        int j = (tid & 3) + q * 4;          // j = which*8 + r*4 + h
        int which = j >> 3, r = (j >> 2) & 1, h = j & 3;
        const float* w = (which ? wed : wes) + r * 512 + h * 128;
        float acc = (which ? ced : ces)[r * 4 + h];
        #pragma unroll 16
        for (int d = 0; d < 128; ++d) acc += xs[node * 132 + d] * w[d];
        float* outp = which ? (r ? ed1 : ed0) : (r ? es1 : es0);
        outp[(size_t)gn * 4 + h] = acc;
    }
}

// ---------- MFMA GEMM per relation (blockIdx.y): gx fs_r section = bf16(xb @ W_r + b_r) ----------
__global__ __launch_bounds__(256) void k_mm(unsigned int* __restrict__ gx,
                                            const unsigned short* __restrict__ wts,
                                            const float* __restrict__ b_src, int n) {
    int rel = blockIdx.y;
    const unsigned short* wT = wts + (size_t)rel * 16384;
    const float* bias = b_src + rel * 128;
    int wid = threadIdx.x >> 6, lane = threadIdx.x & 63;
    int l15 = lane & 15, g = lane >> 4;
    int m0 = blockIdx.x * 128 + wid * 32;
    const unsigned short* Au = (const unsigned short*)gx;   // xb at row*384 + 256
    f32x4 acc[2][8];
    #pragma unroll
    for (int mt = 0; mt < 2; ++mt)
        #pragma unroll
        for (int nt = 0; nt < 8; ++nt)
            #pragma unroll
            for (int r = 0; r < 4; ++r) acc[mt][nt][r] = 0.f;
    #pragma unroll
    for (int t = 0; t < 4; ++t) {
        bf16x8 a0 = *(const bf16x8*)(Au + (size_t)(m0 + l15) * 384 + 256 + t * 32 + g * 8);
        bf16x8 a1 = *(const bf16x8*)(Au + (size_t)(m0 + 16 + l15) * 384 + 256 + t * 32 + g * 8);
        #pragma unroll
        for (int nt = 0; nt < 8; ++nt) {
            bf16x8 b = *(const bf16x8*)(wT + (size_t)(nt * 16 + l15) * 128 + t * 32 + g * 8);
            acc[0][nt] = __builtin_amdgcn_mfma_f32_16x16x32_bf16(a0, b, acc[0][nt], 0, 0, 0);
            acc[1][nt] = __builtin_amdgcn_mfma_f32_16x16x32_bf16(a1, b, acc[1][nt], 0, 0, 0);
        }
    }
    #pragma unroll
    for (int mt = 0; mt < 2; ++mt)
        #pragma unroll
        for (int nt = 0; nt < 8; ++nt) {
            int col = nt * 16 + l15;
            float bv = bias[col];
            #pragma unroll
            for (int r = 0; r < 4; ++r) {
                int row = m0 + mt * 16 + g * 4 + r;
                float v = acc[mt][nt][r] + bv;
                float vp = __shfl_xor(v, 1);
                if (!(l15 & 1) && row < n)
                    gx[(size_t)row * 192 + rel * 64 + (col >> 1)] = bfpack(v, vp);
            }
        }
}

// ---------- merged CSR gather-aggregate: one wave per node; fused relation softmax; bf16 outputs ----------
__global__ __launch_bounds__(256) void k_agg(const int* __restrict__ ip0, const int* __restrict__ srcs0,
                                             const int* __restrict__ ip1, const int* __restrict__ srcs1,
                                             const unsigned int* __restrict__ gx,
                                             const float* __restrict__ es0, const float* __restrict__ es1,
                                             const float* __restrict__ ed0, const float* __restrict__ ed1,
                                             const float* __restrict__ rsdo,
                                             const float* __restrict__ relfeat,
                                             unsigned int* __restrict__ fubp, unsigned int* __restrict__ hgbp, int n) {
    int node = blockIdx.x * 4 + (threadIdx.x >> 6);   // one 64-lane wave per node
    if (node >= n) return;
    int j2 = threadIdx.x & 63;                        // channel pair (2*j2, 2*j2+1)
    int h = j2 >> 4;
    float ed0v = ed0[(size_t)node * 4 + h];
    float ed1v = ed1[(size_t)node * 4 + h];
    float aU0x = 0.f, aU0y = 0.f, aU1x = 0.f, aU1y = 0.f, aHx = 0.f, aHy = 0.f;
    float s0 = 0.f, s1 = 0.f;
    int b0 = ip0[node], e0 = ip0[node + 1];
    #pragma unroll 4
    for (int k = b0; k < e0; ++k) {
        int s = srcs0[k];
        float ex = __expf(leaky(es0[(size_t)s * 4 + h] + ed0v));
        size_t base = (size_t)s * 192;
        unsigned int fv = gx[base + j2];
        unsigned int xv = gx[base + 128 + j2];
        float rs = rsdo[s];
        aU0x += ex * bflo(fv); aU0y += ex * bfhi(fv);
        aHx += rs * bflo(xv); aHy += rs * bfhi(xv);
        s0 += ex;
    }
    int b1 = ip1[node], e1 = ip1[node + 1];
    #pragma unroll 4
    for (int k = b1; k < e1; ++k) {
        int s = srcs1[k];
        float ex = __expf(leaky(es1[(size_t)s * 4 + h] + ed1v));
        size_t base = (size_t)s * 192;
        unsigned int fv = gx[base + 64 + j2];
        unsigned int xv = gx[base + 128 + j2];
        float rs = rsdo[s];
        aU1x += ex * bflo(fv); aU1y += ex * bfhi(fv);
        aHx += rs * bflo(xv); aHy += rs * bfhi(xv);
        s1 += ex;
    }
    float i0 = 1.f / (s0 + 1e-9f), i1 = 1.f / (s1 + 1e-9f);
    float f0x = fmaxf(aU0x * i0, 0.f), f0y = fmaxf(aU0y * i0, 0.f);
    float f1x = fmaxf(aU1x * i1, 0.f), f1y = fmaxf(aU1y * i1, 0.f);
    float sc0 = f0x * relfeat[2 * j2] + f0y * relfeat[2 * j2 + 1];
    float sc1 = f1x * relfeat[128 + 2 * j2] + f1y * relfeat[128 + 2 * j2 + 1];
    #pragma unroll
    for (int m = 1; m < 16; m <<= 1) {
        sc0 += __shfl_xor(sc0, m, 64);
        sc1 += __shfl_xor(sc1, m, 64);
    }
    sc0 = leaky(sc0); sc1 = leaky(sc1);
    float mx = fmaxf(sc0, sc1);
    float p0 = __expf(sc0 - mx), p1 = __expf(sc1 - mx);
    float inv = 1.f / (p0 + p1);
    p0 *= inv; p1 *= inv;
    float rv = rsqrtf(fmaxf((float)((e0 - b0) + (e1 - b1)), 1.f));
    fubp[(size_t)node * 64 + j2] = bfpack(p0 * f0x + p1 * f1x, p0 * f0y + p1 * f1y);
    hgbp[(size_t)node * 64 + j2] = bfpack(aHx * rv, aHy * rv);
}

// ---------- final: two MFMA GEMMs (hgb @ Wg, xb @ Wn) + fusion epilogue ----------
__global__ __launch_bounds__(256) void k_fin(const unsigned int* __restrict__ hgbp,
                                             const unsigned int* __restrict__ gx,
                                             const unsigned short* __restrict__ wtg,
                                             const unsigned short* __restrict__ wtn,
                                             const float* __restrict__ bg, const float* __restrict__ bn,
                                             const unsigned int* __restrict__ fubp,
                                             const float* __restrict__ residual_w, const float* __restrict__ scale_w,
                                             float* __restrict__ out, int n) {
    int wid = threadIdx.x >> 6, lane = threadIdx.x & 63;
    int l15 = lane & 15, g = lane >> 4;
    int m0 = blockIdx.x * 128 + wid * 32;
    const unsigned short* Hu = (const unsigned short*)hgbp;
    const unsigned short* Xu = (const unsigned short*)gx;   // xb at row*384 + 256
    const unsigned short* Fu = (const unsigned short*)fubp;
    f32x4 accn[2][8], accg[2][8];
    #pragma unroll
    for (int mt = 0; mt < 2; ++mt)
        #pragma unroll
        for (int nt = 0; nt < 8; ++nt)
            #pragma unroll
            for (int r = 0; r < 4; ++r) { accn[mt][nt][r] = 0.f; accg[mt][nt][r] = 0.f; }
    #pragma unroll
    for (int t = 0; t < 4; ++t) {
        bf16x8 a0 = *(const bf16x8*)(Xu + (size_t)(m0 + l15) * 384 + 256 + t * 32 + g * 8);
        bf16x8 a1 = *(const bf16x8*)(Xu + (size_t)(m0 + 16 + l15) * 384 + 256 + t * 32 + g * 8);
        #pragma unroll
        for (int nt = 0; nt < 8; ++nt) {
            bf16x8 b = *(const bf16x8*)(wtn + (size_t)(nt * 16 + l15) * 128 + t * 32 + g * 8);
            accn[0][nt] = __builtin_amdgcn_mfma_f32_16x16x32_bf16(a0, b, accn[0][nt], 0, 0, 0);
            accn[1][nt] = __builtin_amdgcn_mfma_f32_16x16x32_bf16(a1, b, accn[1][nt], 0, 0, 0);
        }
    }
    #pragma unroll
    for (int t = 0; t < 4; ++t) {
        bf16x8 a0 = *(const bf16x8*)(Hu + (size_t)(m0 + l15) * 128 + t * 32 + g * 8);
        bf16x8 a1 = *(const bf16x8*)(Hu + (size_t)(m0 + 16 + l15) * 128 + t * 32 + g * 8);
        #pragma unroll
        for (int nt = 0; nt < 8; ++nt) {
            bf16x8 b = *(const bf16x8*)(wtg + (size_t)(nt * 16 + l15) * 128 + t * 32 + g * 8);
            accg[0][nt] = __builtin_amdgcn_mfma_f32_16x16x32_bf16(a0, b, accg[0][nt], 0, 0, 0);
            accg[1][nt] = __builtin_amdgcn_mfma_f32_16x16x32_bf16(a1, b, accg[1][nt], 0, 0, 0);
        }
    }
    float beta = 1.f / (1.f + __expf(-residual_w[0]));
    float av = 1.f / (1.f + __expf(-scale_w[0]));
    #pragma unroll
    for (int mt = 0; mt < 2; ++mt)
        #pragma unroll
        for (int nt = 0; nt < 8; ++nt) {
            int col = nt * 16 + l15;
            float bnv = bn[col], bgv = bg[col];
            #pragma unroll
            for (int r = 0; r < 4; ++r) {
                int row = m0 + mt * 16 + g * 4 + r;
                if (row < n) {
                    float fu = bfs(Fu[(size_t)row * 128 + col]);
                    float fd = accn[mt][nt][r] + bnv;
                    float f = beta * fu + (1.f - beta) * fd;
                    float nl = fmaxf(accg[mt][nt][r] + bgv, 0.f);
                    out[(size_t)row * 128 + col] = av * f + (1.f - av) * nl;
                }
            }
        }
}

extern "C" void kernel_launch(void* const* d_in, const int* in_sizes, int n_in,
                              void* d_out, int out_size, void* d_ws, size_t ws_size,
                              hipStream_t stream) {
    const float* x         = (const float*)d_in[0];
    const int*   src       = (const int*)d_in[1];
    const int*   dst       = (const int*)d_in[2];
    const float* rel_emb   = (const float*)d_in[3];
    const float* W_node    = (const float*)d_in[4];
    const float* b_node    = (const float*)d_in[5];
    const float* W_src     = (const float*)d_in[6];
    const float* b_src     = (const float*)d_in[7];
    const float* W_relT    = (const float*)d_in[8];
    const float* W_relprop = (const float*)d_in[9];
    const float* b_relprop = (const float*)d_in[10];
    const float* W_fuse    = (const float*)d_in[11];
    const float* resid_w   = (const float*)d_in[12];
    const float* scale_w   = (const float*)d_in[13];
    const float* W_g       = (const float*)d_in[14];
    const float* b_g       = (const float*)d_in[15];
    float* out = (float*)d_out;

    const int N = in_sizes[0] / 128;
    const int RE = in_sizes[1];
    const int E = RE / 2;
    const int Npad = (N + 127) & ~127;
    const int NBUCK = (N + 511) >> 9;

    // workspace (~144 MB at N=1e5, E=1e6)
    float* ws = (float*)d_ws;
    size_t o = 0;
    unsigned int* fubp = (unsigned int*)(ws + o); o += (size_t)Npad * 64;   // fused bf16; aliased by sort scratch early
    unsigned int* gx   = (unsigned int*)(ws + o); o += (size_t)Npad * 192;  // fs0|fs1|xb interleaved (768B rows)
    unsigned int* hgbp = (unsigned int*)(ws + o); o += (size_t)Npad * 64;   // bf16 hg*rsdi
    float* es0  = ws + o; o += (size_t)N * 4;
    float* es1  = ws + o; o += (size_t)N * 4;
    float* ed0  = ws + o; o += (size_t)N * 4;
    float* ed1  = ws + o; o += (size_t)N * 4;
    float* rsdo = ws + o; o += N;
    unsigned int* wtu = (unsigned int*)(ws + o); o += 32768;  // bf16 W^T x4 mats
    float* relfeat = ws + o; o += 256;
    float* wes  = ws + o; o += 1024;
    float* wed  = ws + o; o += 1024;
    float* ces  = ws + o; o += 16;
    float* ced  = ws + o; o += 16;
    int* ip0  = (int*)(ws + o); o += N + 1;
    int* ip1  = (int*)(ws + o); o += N + 1;
    int* srcs0 = (int*)(ws + o); o += E;
    int* srcs1 = (int*)(ws + o); o += E;
    int* bucketTot  = (int*)(ws + o); o += 768;
    int* bucketBase = (int*)(ws + o); o += 771;
    int* cursor     = (int*)(ws + o); o += 768;
    // transient sort scratch aliased into fubp region (24 MB <= Npad*256B)
    uint2* pairs0 = (uint2*)fubp;
    uint2* pairs1 = pairs0 + (size_t)E;
    int*   svals  = (int*)(pairs1 + (size_t)E);

    const unsigned short* wts = (const unsigned short*)wtu;  // mat m at wts + m*16384

    hipMemsetAsync(bucketTot, 0, 768 * sizeof(int), stream);

    k_small<<<1, 512, 0, stream>>>(rel_emb, W_relT, W_relprop, b_relprop, W_fuse,
                                   W_src, b_src, W_node, b_node,
                                   relfeat, wes, wed, ces, ced);
    k_twt<<<128, 256, 0, stream>>>(W_src, W_node, W_g, wtu);
    k_count<<<256, 256, 0, stream>>>(src, dst, E, RE, bucketTot);
    k_bases<<<1, 256, 0, stream>>>(bucketTot, bucketBase, cursor, ip0, ip1, N, E);
    k_cscatter<<<256, 256, 0, stream>>>(src, dst, E, RE, cursor, pairs0, pairs1, svals);
    k_fine<<<dim3(NBUCK, 3), 512, 0, stream>>>(pairs0, pairs1, svals, bucketBase,
                                               ip0, ip1, srcs0, srcs1, rsdo, N);

    k_prep<<<(N + 63) / 64, 256, 0, stream>>>(x, wes, wed, ces, ced, es0, es1, ed0, ed1, gx, N);

    k_mm<<<dim3(Npad / 128, 2), 256, 0, stream>>>(gx, wts, b_src, N);

    k_agg<<<(N + 3) / 4, 256, 0, stream>>>(ip0, srcs0, ip1, srcs1, gx,
                                           es0, es1, ed0, ed1, rsdo, relfeat, fubp, hgbp, N);

    k_fin<<<Npad / 128, 256, 0, stream>>>(hgbp, gx, wts + 3 * 16384, wts + 2 * 16384,
                                          b_g, b_node, fubp, resid_w, scale_w, out, N);
}

// Round 12
// 489.928 us; speedup vs baseline: 1.1087x; 1.0460x over previous
//
#include <hip/hip_runtime.h>
#include <cstddef>

#define NEG_SLOPE 0.2f

typedef __attribute__((ext_vector_type(8))) short bf16x8;
typedef __attribute__((ext_vector_type(4))) float f32x4;

__device__ __forceinline__ float leaky(float v) { return v >= 0.f ? v : NEG_SLOPE * v; }

__device__ __forceinline__ unsigned int bfpack(float a, float b) {
    unsigned int ua = __float_as_uint(a);
    ua += 0x7fffu + ((ua >> 16) & 1u);
    unsigned int ub = __float_as_uint(b);
    ub += 0x7fffu + ((ub >> 16) & 1u);
    return (ua >> 16) | (ub & 0xffff0000u);
}
__device__ __forceinline__ float bflo(unsigned int u) { return __uint_as_float(u << 16); }
__device__ __forceinline__ float bfhi(unsigned int u) { return __uint_as_float(u & 0xffff0000u); }
__device__ __forceinline__ float bfs(unsigned short u) { return __uint_as_float(((unsigned int)u) << 16); }

#define NCB 192   // coarse count/scatter blocks

// ================= K1: small-constants (b==0) | weight transpose (b in [1,64]) | coarse count (b>=65) =================
__global__ __launch_bounds__(512) void k_init(const float* __restrict__ rel_emb, const float* __restrict__ W_relT,
                                              const float* __restrict__ W_relprop, const float* __restrict__ b_relprop,
                                              const float* __restrict__ W_fuse, const float* __restrict__ W_src,
                                              const float* __restrict__ b_src, const float* __restrict__ W_node,
                                              const float* __restrict__ b_node, const float* __restrict__ W_g,
                                              const int* __restrict__ src, const int* __restrict__ dst,
                                              int E, int RE,
                                              float* __restrict__ relfeat, float* __restrict__ wes,
                                              float* __restrict__ wed, float* __restrict__ ces, float* __restrict__ ced,
                                              unsigned int* __restrict__ wt, int* __restrict__ bucketTot) {
    __shared__ float av[512];
    __shared__ float rp[2][128];
    __shared__ int h0[256], h1[256], h2[256];
    int b = blockIdx.x;
    int t = threadIdx.x;
    if (b == 0) {
        // ---- tiny per-relation constants + attention-vector projections (512 threads) ----
        {
            int r = t >> 8, m = t & 255;
            float acc = 0.f;
            const float* re = rel_emb + r * 64;
            const float* w = W_relT + (size_t)r * 16384 + m;
            #pragma unroll 8
            for (int k = 0; k < 64; ++k) acc += re[k] * w[(size_t)k * 256];
            av[t] = acc;
        }
        if (t < 256) {
            int r = t >> 7, m = t & 127;
            float acc = b_relprop[t];
            const float* re = rel_emb + r * 64;
            const float* w = W_relprop + (size_t)r * 8192 + m;
            #pragma unroll 8
            for (int k = 0; k < 64; ++k) acc += re[k] * w[(size_t)k * 128];
            rp[r][m] = acc;
        }
        __syncthreads();
        if (t < 256) {
            int r = t >> 7, h = (t >> 5) & 3, d = t & 31;
            float acc = 0.f;
            const float* w = W_fuse + ((size_t)(r * 4 + h) * 32) * 32 + d;
            #pragma unroll
            for (int k = 0; k < 32; ++k) acc += rp[r][h * 32 + k] * w[(size_t)k * 32];
            relfeat[t] = acc;
        }
        for (int idx = t; idx < 2048; idx += 512) {
            int which = idx >> 10, rem = idx & 1023;
            int r = rem >> 9, h = (rem >> 7) & 3, c = rem & 127;
            const float* W = which ? W_node : (W_src + (size_t)r * 16384);
            const float* a = av + r * 256 + h * 64 + which * 32;
            float acc = 0.f;
            #pragma unroll
            for (int d = 0; d < 32; ++d) acc += W[(size_t)c * 128 + h * 32 + d] * a[d];
            (which ? wed : wes)[rem] = acc;
        }
        if (t < 16) {
            int which = t >> 3, r = (t >> 2) & 1, h = t & 3;
            const float* bb = which ? b_node : (b_src + r * 128);
            const float* a = av + r * 256 + h * 64 + which * 32;
            float acc = 0.f;
            #pragma unroll
            for (int d = 0; d < 32; ++d) acc += bb[h * 32 + d] * a[d];
            (which ? ced : ces)[r * 4 + h] = acc;
        }
    } else if (b <= 64) {
        // ---- bf16 W^T transpose: wt[mat][n][k] ----
        int idx = (b - 1) * 512 + t;   // 4*128*64 = 32768
        int mat = idx >> 13, rem = idx & 8191;
        int nrow = rem >> 6, kp = rem & 63;
        const float* W = mat < 2 ? W_src + (size_t)mat * 16384 : (mat == 2 ? W_node : W_g);
        wt[idx] = bfpack(W[(size_t)(2 * kp) * 128 + nrow], W[(size_t)(2 * kp + 1) * 128 + nrow]);
    } else {
        // ---- coarse bucket counts (single pass over src+dst) ----
        if (t < 256) { h0[t] = 0; h1[t] = 0; h2[t] = 0; }
        __syncthreads();
        int cb = b - 65;
        int chunk = (RE + NCB - 1) / NCB;
        int lo = cb * chunk, hi = min(lo + chunk, RE);
        for (int i = lo + t; i < hi; i += 512) {
            int d = dst[i], s = src[i];
            atomicAdd((i < E ? h0 : h1) + (d >> 9), 1);
            atomicAdd(&h2[s >> 9], 1);
        }
        __syncthreads();
        if (t < 256) {
            if (h0[t]) atomicAdd(&bucketTot[t], h0[t]);
            if (h1[t]) atomicAdd(&bucketTot[256 + t], h1[t]);
            if (h2[t]) atomicAdd(&bucketTot[512 + t], h2[t]);
        }
    }
}

// ================= K2: bucket-scan (b==0) | prep scores + xb (b>=1) =================
__global__ __launch_bounds__(256) void k_prepb(const int* __restrict__ bucketTot,
                                               int* __restrict__ bucketBase, int* __restrict__ cursor,
                                               int* __restrict__ ip0, int* __restrict__ ip1, int E,
                                               const float* __restrict__ x,
                                               const float* __restrict__ wes, const float* __restrict__ wed,
                                               const float* __restrict__ ces, const float* __restrict__ ced,
                                               float* __restrict__ es0, float* __restrict__ es1,
                                               float* __restrict__ ed0, float* __restrict__ ed1,
                                               unsigned int* __restrict__ gx, int n) {
    __shared__ float xs[64 * 132];
    int tid = threadIdx.x;
    if (blockIdx.x == 0) {
        __shared__ int sc[256];
        int t = tid;
        for (int j = 0; j < 3; ++j) {
            int v = bucketTot[j * 256 + t];
            sc[t] = v;
            __syncthreads();
            for (int off = 1; off < 256; off <<= 1) {
                int tmp = (t >= off) ? sc[t - off] : 0;
                __syncthreads();
                sc[t] += tmp;
                __syncthreads();
            }
            int excl = sc[t] - v;
            bucketBase[j * 257 + t] = excl;
            if (t == 255) bucketBase[j * 257 + 256] = sc[255];
            cursor[j * 256 + t] = excl;
            __syncthreads();
        }
        if (t == 0) { ip0[n] = E; ip1[n] = E; }
        return;
    }
    int nb0 = (blockIdx.x - 1) * 64;
    for (int i = tid; i < 64 * 32; i += 256) {
        int row = i >> 5, c4 = i & 31;
        float4 v = make_float4(0.f, 0.f, 0.f, 0.f);
        if (nb0 + row < n) v = *(const float4*)(x + (size_t)(nb0 + row) * 128 + c4 * 4);
        *(float4*)(xs + row * 132 + c4 * 4) = v;
    }
    __syncthreads();
    for (int i = tid; i < 64 * 64; i += 256) {
        int row = i >> 6, c2 = i & 63;
        int gr = nb0 + row;
        if (gr < n)
            gx[(size_t)gr * 192 + 128 + c2] = bfpack(xs[row * 132 + 2 * c2], xs[row * 132 + 2 * c2 + 1]);
    }
    int node = tid >> 2;
    int gn = nb0 + node;
    if (gn >= n) return;
    #pragma unroll
    for (int q = 0; q < 4; ++q) {
        int j = (tid & 3) + q * 4;          // j = which*8 + r*4 + h
        int which = j >> 3, r = (j >> 2) & 1, h = j & 3;
        const float* w = (which ? wed : wes) + r * 512 + h * 128;
        float acc = (which ? ced : ces)[r * 4 + h];
        #pragma unroll 16
        for (int d = 0; d < 128; ++d) acc += xs[node * 132 + d] * w[d];
        float* outp = which ? (r ? ed1 : ed0) : (r ? es1 : es0);
        outp[(size_t)gn * 4 + h] = acc;
    }
}

// ================= K3: coarse scatter (b<NCB) | dual-relation MFMA GEMM (b>=NCB) =================
__global__ __launch_bounds__(256) void k_scmm(const int* __restrict__ src, const int* __restrict__ dst,
                                              int E, int RE, int* __restrict__ cursor,
                                              uint2* __restrict__ pairs0, uint2* __restrict__ pairs1,
                                              int* __restrict__ svals,
                                              unsigned int* __restrict__ gx,
                                              const unsigned short* __restrict__ wts,
                                              const float* __restrict__ b_src, int MB, int n) {
    if (blockIdx.x < NCB) {
        __shared__ int h0[256], h1[256], h2[256];
        __shared__ int c0[256], c1[256], c2[256];
        int t = threadIdx.x;
        h0[t] = 0; h1[t] = 0; h2[t] = 0;
        __syncthreads();
        int chunk = (RE + NCB - 1) / NCB;
        int lo = blockIdx.x * chunk, hi = min(lo + chunk, RE);
        for (int i = lo + t; i < hi; i += 256) {
            int d = dst[i], s = src[i];
            atomicAdd((i < E ? h0 : h1) + (d >> 9), 1);
            atomicAdd(&h2[s >> 9], 1);
        }
        __syncthreads();
        if (h0[t]) c0[t] = atomicAdd(&cursor[t], h0[t]);
        if (h1[t]) c1[t] = atomicAdd(&cursor[256 + t], h1[t]);
        if (h2[t]) c2[t] = atomicAdd(&cursor[512 + t], h2[t]);
        __syncthreads();
        for (int i = lo + t; i < hi; i += 256) {
            int d = dst[i], s = src[i];
            if (i < E) {
                int pos = atomicAdd(&c0[d >> 9], 1);
                pairs0[pos] = make_uint2((unsigned)s, (unsigned)d);
            } else {
                int pos = atomicAdd(&c1[d >> 9], 1);
                pairs1[pos] = make_uint2((unsigned)s, (unsigned)d);
            }
            int pos2 = atomicAdd(&c2[s >> 9], 1);
            svals[pos2] = s;
        }
        return;
    }
    int q = blockIdx.x - NCB;
    int rel = q / MB, mb = q % MB;
    const unsigned short* wT = wts + (size_t)rel * 16384;
    const float* bias = b_src + rel * 128;
    int wid = threadIdx.x >> 6, lane = threadIdx.x & 63;
    int l15 = lane & 15, g = lane >> 4;
    int m0 = mb * 128 + wid * 32;
    const unsigned short* Au = (const unsigned short*)gx;   // xb at row*384 + 256
    f32x4 acc[2][8];
    #pragma unroll
    for (int mt = 0; mt < 2; ++mt)
        #pragma unroll
        for (int nt = 0; nt < 8; ++nt)
            #pragma unroll
            for (int r = 0; r < 4; ++r) acc[mt][nt][r] = 0.f;
    #pragma unroll
    for (int t = 0; t < 4; ++t) {
        bf16x8 a0 = *(const bf16x8*)(Au + (size_t)(m0 + l15) * 384 + 256 + t * 32 + g * 8);
        bf16x8 a1 = *(const bf16x8*)(Au + (size_t)(m0 + 16 + l15) * 384 + 256 + t * 32 + g * 8);
        #pragma unroll
        for (int nt = 0; nt < 8; ++nt) {
            bf16x8 b = *(const bf16x8*)(wT + (size_t)(nt * 16 + l15) * 128 + t * 32 + g * 8);
            acc[0][nt] = __builtin_amdgcn_mfma_f32_16x16x32_bf16(a0, b, acc[0][nt], 0, 0, 0);
            acc[1][nt] = __builtin_amdgcn_mfma_f32_16x16x32_bf16(a1, b, acc[1][nt], 0, 0, 0);
        }
    }
    #pragma unroll
    for (int mt = 0; mt < 2; ++mt)
        #pragma unroll
        for (int nt = 0; nt < 8; ++nt) {
            int col = nt * 16 + l15;
            float bv = bias[col];
            #pragma unroll
            for (int r = 0; r < 4; ++r) {
                int row = m0 + mt * 16 + g * 4 + r;
                float v = acc[mt][nt][r] + bv;
                float vp = __shfl_xor(v, 1);
                if (!(l15 & 1) && row < n)
                    gx[(size_t)row * 192 + rel * 64 + (col >> 1)] = bfpack(v, vp);
            }
        }
}

// ---------- stage 4 (3 jobs): per-bucket fine sort (r=0,1) + src out-degree -> rsdo (r=2) ----------
__global__ __launch_bounds__(512) void k_fine(const uint2* __restrict__ pairs0, const uint2* __restrict__ pairs1,
                                              const int* __restrict__ svals,
                                              const int* __restrict__ bucketBase,
                                              int* __restrict__ ip0, int* __restrict__ ip1,
                                              int* __restrict__ srcs0, int* __restrict__ srcs1,
                                              float* __restrict__ rsdo, int N) {
    int r = blockIdx.y;
    int b = blockIdx.x;
    __shared__ int hist[512];
    int t = threadIdx.x;
    hist[t] = 0;
    __syncthreads();
    if (r == 2) {   // src out-degree histogram
        int ebase = bucketBase[2 * 257 + b], eend = bucketBase[2 * 257 + b + 1];
        for (int k = ebase + t; k < eend; k += 512)
            atomicAdd(&hist[svals[k] & 511], 1);
        __syncthreads();
        int node = (b << 9) + t;
        if (node < N) rsdo[node] = rsqrtf(fmaxf((float)hist[t], 1.f));
        return;
    }
    const uint2* pairs = r ? pairs1 : pairs0;
    int* ip = r ? ip1 : ip0;
    int* srcs = r ? srcs1 : srcs0;
    int ebase = bucketBase[r * 257 + b], eend = bucketBase[r * 257 + b + 1];
    for (int k = ebase + t; k < eend; k += 512)
        atomicAdd(&hist[pairs[k].y & 511], 1);
    __syncthreads();
    int v = hist[t];
    for (int off = 1; off < 512; off <<= 1) {
        int tmp = (t >= off) ? hist[t - off] : 0;
        __syncthreads();
        hist[t] += tmp;
        __syncthreads();
    }
    int excl = hist[t] - v;
    int node = (b << 9) + t;
    if (node < N) ip[node] = ebase + excl;
    __syncthreads();
    hist[t] = ebase + excl;  // reuse as scatter cursor
    __syncthreads();
    for (int k = ebase + t; k < eend; k += 512) {
        uint2 p = pairs[k];
        int pos = atomicAdd(&hist[p.y & 511], 1);
        srcs[pos] = (int)p.x;
    }
}

// ---------- merged CSR gather-aggregate: one wave per node; fused relation softmax; bf16 outputs ----------
__global__ __launch_bounds__(256) void k_agg(const int* __restrict__ ip0, const int* __restrict__ srcs0,
                                             const int* __restrict__ ip1, const int* __restrict__ srcs1,
                                             const unsigned int* __restrict__ gx,
                                             const float* __restrict__ es0, const float* __restrict__ es1,
                                             const float* __restrict__ ed0, const float* __restrict__ ed1,
                                             const float* __restrict__ rsdo,
                                             const float* __restrict__ relfeat,
                                             unsigned int* __restrict__ fubp, unsigned int* __restrict__ hgbp, int n) {
    int node = blockIdx.x * 4 + (threadIdx.x >> 6);   // one 64-lane wave per node
    if (node >= n) return;
    int j2 = threadIdx.x & 63;                        // channel pair (2*j2, 2*j2+1)
    int h = j2 >> 4;
    float ed0v = ed0[(size_t)node * 4 + h];
    float ed1v = ed1[(size_t)node * 4 + h];
    float aU0x = 0.f, aU0y = 0.f, aU1x = 0.f, aU1y = 0.f, aHx = 0.f, aHy = 0.f;
    float s0 = 0.f, s1 = 0.f;
    int b0 = ip0[node], e0 = ip0[node + 1];
    #pragma unroll 4
    for (int k = b0; k < e0; ++k) {
        int s = srcs0[k];
        float ex = __expf(leaky(es0[(size_t)s * 4 + h] + ed0v));
        size_t base = (size_t)s * 192;
        unsigned int fv = gx[base + j2];
        unsigned int xv = gx[base + 128 + j2];
        float rs = rsdo[s];
        aU0x += ex * bflo(fv); aU0y += ex * bfhi(fv);
        aHx += rs * bflo(xv); aHy += rs * bfhi(xv);
        s0 += ex;
    }
    int b1 = ip1[node], e1 = ip1[node + 1];
    #pragma unroll 4
    for (int k = b1; k < e1; ++k) {
        int s = srcs1[k];
        float ex = __expf(leaky(es1[(size_t)s * 4 + h] + ed1v));
        size_t base = (size_t)s * 192;
        unsigned int fv = gx[base + 64 + j2];
        unsigned int xv = gx[base + 128 + j2];
        float rs = rsdo[s];
        aU1x += ex * bflo(fv); aU1y += ex * bfhi(fv);
        aHx += rs * bflo(xv); aHy += rs * bfhi(xv);
        s1 += ex;
    }
    float i0 = 1.f / (s0 + 1e-9f), i1 = 1.f / (s1 + 1e-9f);
    float f0x = fmaxf(aU0x * i0, 0.f), f0y = fmaxf(aU0y * i0, 0.f);
    float f1x = fmaxf(aU1x * i1, 0.f), f1y = fmaxf(aU1y * i1, 0.f);
    float sc0 = f0x * relfeat[2 * j2] + f0y * relfeat[2 * j2 + 1];
    float sc1 = f1x * relfeat[128 + 2 * j2] + f1y * relfeat[128 + 2 * j2 + 1];
    #pragma unroll
    for (int m = 1; m < 16; m <<= 1) {
        sc0 += __shfl_xor(sc0, m, 64);
        sc1 += __shfl_xor(sc1, m, 64);
    }
    sc0 = leaky(sc0); sc1 = leaky(sc1);
    float mx = fmaxf(sc0, sc1);
    float p0 = __expf(sc0 - mx), p1 = __expf(sc1 - mx);
    float inv = 1.f / (p0 + p1);
    p0 *= inv; p1 *= inv;
    float rv = rsqrtf(fmaxf((float)((e0 - b0) + (e1 - b1)), 1.f));
    fubp[(size_t)node * 64 + j2] = bfpack(p0 * f0x + p1 * f1x, p0 * f0y + p1 * f1y);
    hgbp[(size_t)node * 64 + j2] = bfpack(aHx * rv, aHy * rv);
}

// ---------- final: two MFMA GEMMs (hgb @ Wg, xb @ Wn) + fusion epilogue ----------
__global__ __launch_bounds__(256) void k_fin(const unsigned int* __restrict__ hgbp,
                                             const unsigned int* __restrict__ gx,
                                             const unsigned short* __restrict__ wtg,
                                             const unsigned short* __restrict__ wtn,
                                             const float* __restrict__ bg, const float* __restrict__ bn,
                                             const unsigned int* __restrict__ fubp,
                                             const float* __restrict__ residual_w, const float* __restrict__ scale_w,
                                             float* __restrict__ out, int n) {
    int wid = threadIdx.x >> 6, lane = threadIdx.x & 63;
    int l15 = lane & 15, g = lane >> 4;
    int m0 = blockIdx.x * 128 + wid * 32;
    const unsigned short* Hu = (const unsigned short*)hgbp;
    const unsigned short* Xu = (const unsigned short*)gx;   // xb at row*384 + 256
    const unsigned short* Fu = (const unsigned short*)fubp;
    f32x4 accn[2][8], accg[2][8];
    #pragma unroll
    for (int mt = 0; mt < 2; ++mt)
        #pragma unroll
        for (int nt = 0; nt < 8; ++nt)
            #pragma unroll
            for (int r = 0; r < 4; ++r) { accn[mt][nt][r] = 0.f; accg[mt][nt][r] = 0.f; }
    #pragma unroll
    for (int t = 0; t < 4; ++t) {
        bf16x8 a0 = *(const bf16x8*)(Xu + (size_t)(m0 + l15) * 384 + 256 + t * 32 + g * 8);
        bf16x8 a1 = *(const bf16x8*)(Xu + (size_t)(m0 + 16 + l15) * 384 + 256 + t * 32 + g * 8);
        #pragma unroll
        for (int nt = 0; nt < 8; ++nt) {
            bf16x8 b = *(const bf16x8*)(wtn + (size_t)(nt * 16 + l15) * 128 + t * 32 + g * 8);
            accn[0][nt] = __builtin_amdgcn_mfma_f32_16x16x32_bf16(a0, b, accn[0][nt], 0, 0, 0);
            accn[1][nt] = __builtin_amdgcn_mfma_f32_16x16x32_bf16(a1, b, accn[1][nt], 0, 0, 0);
        }
    }
    #pragma unroll
    for (int t = 0; t < 4; ++t) {
        bf16x8 a0 = *(const bf16x8*)(Hu + (size_t)(m0 + l15) * 128 + t * 32 + g * 8);
        bf16x8 a1 = *(const bf16x8*)(Hu + (size_t)(m0 + 16 + l15) * 128 + t * 32 + g * 8);
        #pragma unroll
        for (int nt = 0; nt < 8; ++nt) {
            bf16x8 b = *(const bf16x8*)(wtg + (size_t)(nt * 16 + l15) * 128 + t * 32 + g * 8);
            accg[0][nt] = __builtin_amdgcn_mfma_f32_16x16x32_bf16(a0, b, accg[0][nt], 0, 0, 0);
            accg[1][nt] = __builtin_amdgcn_mfma_f32_16x16x32_bf16(a1, b, accg[1][nt], 0, 0, 0);
        }
    }
    float beta = 1.f / (1.f + __expf(-residual_w[0]));
    float av = 1.f / (1.f + __expf(-scale_w[0]));
    #pragma unroll
    for (int mt = 0; mt < 2; ++mt)
        #pragma unroll
        for (int nt = 0; nt < 8; ++nt) {
            int col = nt * 16 + l15;
            float bnv = bn[col], bgv = bg[col];
            #pragma unroll
            for (int r = 0; r < 4; ++r) {
                int row = m0 + mt * 16 + g * 4 + r;
                if (row < n) {
                    float fu = bfs(Fu[(size_t)row * 128 + col]);
                    float fd = accn[mt][nt][r] + bnv;
                    float f = beta * fu + (1.f - beta) * fd;
                    float nl = fmaxf(accg[mt][nt][r] + bgv, 0.f);
                    out[(size_t)row * 128 + col] = av * f + (1.f - av) * nl;
                }
            }
        }
}

extern "C" void kernel_launch(void* const* d_in, const int* in_sizes, int n_in,
                              void* d_out, int out_size, void* d_ws, size_t ws_size,
                              hipStream_t stream) {
    const float* x         = (const float*)d_in[0];
    const int*   src       = (const int*)d_in[1];
    const int*   dst       = (const int*)d_in[2];
    const float* rel_emb   = (const float*)d_in[3];
    const float* W_node    = (const float*)d_in[4];
    const float* b_node    = (const float*)d_in[5];
    const float* W_src     = (const float*)d_in[6];
    const float* b_src     = (const float*)d_in[7];
    const float* W_relT    = (const float*)d_in[8];
    const float* W_relprop = (const float*)d_in[9];
    const float* b_relprop = (const float*)d_in[10];
    const float* W_fuse    = (const float*)d_in[11];
    const float* resid_w   = (const float*)d_in[12];
    const float* scale_w   = (const float*)d_in[13];
    const float* W_g       = (const float*)d_in[14];
    const float* b_g       = (const float*)d_in[15];
    float* out = (float*)d_out;

    const int N = in_sizes[0] / 128;
    const int RE = in_sizes[1];
    const int E = RE / 2;
    const int Npad = (N + 127) & ~127;
    const int NBUCK = (N + 511) >> 9;
    const int MB = Npad / 128;

    // workspace (~144 MB at N=1e5, E=1e6)
    float* ws = (float*)d_ws;
    size_t o = 0;
    unsigned int* fubp = (unsigned int*)(ws + o); o += (size_t)Npad * 64;   // fused bf16; aliased by sort scratch early
    unsigned int* gx   = (unsigned int*)(ws + o); o += (size_t)Npad * 192;  // fs0|fs1|xb interleaved (768B rows)
    unsigned int* hgbp = (unsigned int*)(ws + o); o += (size_t)Npad * 64;   // bf16 hg*rsdi
    float* es0  = ws + o; o += (size_t)N * 4;
    float* es1  = ws + o; o += (size_t)N * 4;
    float* ed0  = ws + o; o += (size_t)N * 4;
    float* ed1  = ws + o; o += (size_t)N * 4;
    float* rsdo = ws + o; o += N;
    unsigned int* wtu = (unsigned int*)(ws + o); o += 32768;  // bf16 W^T x4 mats
    float* relfeat = ws + o; o += 256;
    float* wes  = ws + o; o += 1024;
    float* wed  = ws + o; o += 1024;
    float* ces  = ws + o; o += 16;
    float* ced  = ws + o; o += 16;
    int* ip0  = (int*)(ws + o); o += N + 1;
    int* ip1  = (int*)(ws + o); o += N + 1;
    int* srcs0 = (int*)(ws + o); o += E;
    int* srcs1 = (int*)(ws + o); o += E;
    int* bucketTot  = (int*)(ws + o); o += 768;
    int* bucketBase = (int*)(ws + o); o += 771;
    int* cursor     = (int*)(ws + o); o += 768;
    // transient sort scratch aliased into fubp region (24 MB <= Npad*256B)
    uint2* pairs0 = (uint2*)fubp;
    uint2* pairs1 = pairs0 + (size_t)E;
    int*   svals  = (int*)(pairs1 + (size_t)E);

    const unsigned short* wts = (const unsigned short*)wtu;  // mat m at wts + m*16384

    hipMemsetAsync(bucketTot, 0, 768 * sizeof(int), stream);

    // K1: small | twt | count
    k_init<<<1 + 64 + NCB, 512, 0, stream>>>(rel_emb, W_relT, W_relprop, b_relprop, W_fuse,
                                             W_src, b_src, W_node, b_node, W_g,
                                             src, dst, E, RE,
                                             relfeat, wes, wed, ces, ced, wtu, bucketTot);
    // K2: bases | prep
    k_prepb<<<1 + (N + 63) / 64, 256, 0, stream>>>(bucketTot, bucketBase, cursor, ip0, ip1, E,
                                                   x, wes, wed, ces, ced,
                                                   es0, es1, ed0, ed1, gx, N);
    // K3: cscatter | mm
    k_scmm<<<NCB + 2 * MB, 256, 0, stream>>>(src, dst, E, RE, cursor, pairs0, pairs1, svals,
                                             gx, wts, b_src, MB, N);

    k_fine<<<dim3(NBUCK, 3), 512, 0, stream>>>(pairs0, pairs1, svals, bucketBase,
                                               ip0, ip1, srcs0, srcs1, rsdo, N);

    k_agg<<<(N + 3) / 4, 256, 0, stream>>>(ip0, srcs0, ip1, srcs1, gx,
                                           es0, es1, ed0, ed1, rsdo, relfeat, fubp, hgbp, N);

    k_fin<<<MB, 256, 0, stream>>>(hgbp, gx, wts + 3 * 16384, wts + 2 * 16384,
                                  b_g, b_node, fubp, resid_w, scale_w, out, N);
}